// Round 12
// baseline (49.066 us; speedup 1.0000x reference)
//
#include <hip/hip_runtime.h>
#include <math.h>
#include <stdint.h>

#define BB 256
#define TT 512
#define KK 20
#define START_TAG 18
#define STOP_TAG 19
#define NST 400
#define SEGSTRIDE 420        // 400 M + 20 col-exponents
#define WS_SEG_OFF 4096      // floats: partialA[256] + partialG[2048] + pad

typedef __bf16 bf16x8 __attribute__((ext_vector_type(8)));
typedef float f32x16 __attribute__((ext_vector_type(16)));
typedef uint32_t u32x4 __attribute__((ext_vector_type(4)));

__device__ __forceinline__ float fexp2(float x){ float r; asm("v_exp_f32 %0, %1":"=v"(r):"v"(x)); return r; }
__device__ __forceinline__ float flog2(float x){ float r; asm("v_log_f32 %0, %1":"=v"(r):"v"(x)); return r; }
__device__ __forceinline__ uint32_t pk_bf16(float lo, float hi){
  uint32_t r; asm("v_cvt_pk_bf16_f32 %0, %1, %2":"=v"(r):"v"(lo),"v"(hi)); return r;
}
__device__ __forceinline__ void pswap(uint32_t &a, uint32_t &b){
  asm("v_permlane32_swap_b32 %0, %1":"+v"(a),"+v"(b));
}
__device__ __forceinline__ f32x16 mfma_bf16(u32x4 a, u32x4 b, f32x16 c){
  return __builtin_amdgcn_mfma_f32_32x32x16_bf16(
    __builtin_bit_cast(bf16x8,a), __builtin_bit_cast(bf16x8,b), c, 0,0,0);
}

// ============ pass 1: segment 20x20 matrix products via MFMA + fused gold ====
// ONE task (= SEGL consecutive steps) per wave. 4 NAMED row buffers, loop
// unrolled x4 (no register rotation -> counted vmcnt, loads stay in flight).
// Gold gather fused: t is wave-uniform per step, so tgt/prev are uniform;
// the matching lane extracts f[b,t,tgt,prev] from the RAW loaded registers.
// C->B via cvt_pk + permlane32_swap (C/D layout verified R7/R8).
template<int SEGL, int SEGS>
__global__ __launch_bounds__(64) void seg_mfma(
    const float* __restrict__ feats, const int* __restrict__ targets,
    const int* __restrict__ lengths, float* __restrict__ wseg,
    float* __restrict__ partialG)
{
  constexpr float LOG2E = 1.4426950408889634f;
  const int lane = threadIdx.x;
  const int n  = lane & 31;    // A-row / C-col
  const int hi = lane >> 5;    // k-block selector
  const int task = blockIdx.x;
  const int b = task / SEGS;
  const int s = task - b*SEGS;
  const int seg0 = 1 + SEGL*s;
  const int len = lengths[b];
  int nv = len - seg0; nv = nv < 0 ? 0 : (nv > SEGL ? SEGL : nv);
  if (nv <= 0){ if (lane == 0) partialG[task] = 0.f; return; }   // wave-uniform

  const bool rowok = n < KK;
  const int rli = rowok ? n : 0;               // clamp addr, zero later
  const float* rbase = feats + (size_t)(b*TT + seg0)*NST + rli*KK;
  const int off0 = hi ? 8 : 0;
  const int bT = b*TT;

  // ---- identity B (bf16), pad zero ----
  u32x4 B0, B1;
  #pragma unroll
  for (int d=0; d<4; ++d){
    int k0 = hi*8 + 2*d;
    uint32_t v = 0;
    if (k0   == n && n < KK) v |= 0x3F80u;
    if (k0+1 == n && n < KK) v |= 0x3F800000u;
    B0[d] = v;
    int m0 = 16 + hi*8 + 2*d;
    uint32_t u = 0;
    if (m0   == n && n < KK) u |= 0x3F80u;
    if (m0+1 == n && n < KK) u |= 0x3F800000u;
    B1[d] = u;
  }

  int cexp = 0;
  float gold = 0.f;
  f32x16 acc;
  #pragma unroll
  for (int r=0;r<16;++r) acc[r] = 0.f;

  auto LDr = [&](int it, float4 &r0, float4 &r1, float4 &r2){
    const float* p = rbase + (size_t)it*NST;
    r0 = *(const float4*)(p + off0);
    r1 = *(const float4*)(p + off0 + 4);
    r2 = (hi == 0) ? *(const float4*)(p + 16) : make_float4(0.f,0.f,0.f,0.f);
  };

  auto RENORM = [&](){
    float mx = acc[0];
    #pragma unroll
    for (int r=1;r<16;++r) mx = fmaxf(mx, acc[r]);
    mx = fmaxf(mx, __shfl_xor(mx, 32, 64));
    int e = (int)((__float_as_uint(mx) >> 23) & 255) - 127;
    if (e < -100) e = -100;
    float sc = __uint_as_float((uint32_t)(127 - e) << 23);
    #pragma unroll
    for (int r=0;r<16;++r) acc[r] *= sc;
    cexp += e;
  };

  auto BODY = [&](float4 &r0, float4 &r1, float4 &r2, int it){
    // ---- fused gold gather (uniform tgt/prev; raw values) ----
    int t   = seg0 + it;
    int tgt = targets[bT + t];
    int prv = targets[bT + t - 1];
    int hsel = (prv >= 8 && prv < 16) ? 1 : 0;
    int rsel = (prv >= 16) ? 2 : (((prv & 7) >= 4) ? 1 : 0);
    int comp = prv & 3;
    float4 rr = (rsel == 0) ? r0 : ((rsel == 1) ? r1 : r2);
    float vv = (comp==0)?rr.x:((comp==1)?rr.y:((comp==2)?rr.z:rr.w));
    if (n == tgt && hi == hsel) gold += vv;
    // ---- exp2 -> bf16 A fragment ----
    uint32_t w0 = pk_bf16(fexp2(r0.x*LOG2E), fexp2(r0.y*LOG2E));
    uint32_t w1 = pk_bf16(fexp2(r0.z*LOG2E), fexp2(r0.w*LOG2E));
    uint32_t w2 = pk_bf16(fexp2(r1.x*LOG2E), fexp2(r1.y*LOG2E));
    uint32_t w3 = pk_bf16(fexp2(r1.z*LOG2E), fexp2(r1.w*LOG2E));
    uint32_t w4 = pk_bf16(fexp2(r2.x*LOG2E), fexp2(r2.y*LOG2E));
    uint32_t w5 = pk_bf16(fexp2(r2.z*LOG2E), fexp2(r2.w*LOG2E));
    if (!rowok){ w0=0u; w1=0u; w2=0u; w3=0u; }
    if (!(rowok && hi==0)){ w4=0u; w5=0u; }
    u32x4 A0, A1;
    A0[0]=w0; A0[1]=w1; A0[2]=w2; A0[3]=w3;
    A1[0]=w4; A1[1]=w5; A1[2]=0u; A1[3]=0u;
    f32x16 z;
    #pragma unroll
    for (int r=0;r<16;++r) z[r] = 0.f;
    acc = mfma_bf16(A0, B0, z);
    acc = mfma_bf16(A1, B1, acc);
    if (it != nv-1){
      if ((it & 7) == 7) RENORM();
      // ---- C -> B (bf16) via cvt_pk + permlane32_swap ----
      uint32_t x0 = pk_bf16(acc[0],  acc[1]);
      uint32_t x1 = pk_bf16(acc[2],  acc[3]);
      uint32_t x2 = pk_bf16(acc[4],  acc[5]);
      uint32_t x3 = pk_bf16(acc[6],  acc[7]);
      uint32_t x4 = pk_bf16(acc[8],  acc[9]);
      uint32_t x5 = pk_bf16(acc[10], acc[11]);
      uint32_t x6 = pk_bf16(acc[12], acc[13]);
      uint32_t x7 = pk_bf16(acc[14], acc[15]);
      pswap(x0,x2); pswap(x1,x3); pswap(x4,x6); pswap(x5,x7);
      B0[0]=x0; B0[1]=x1; B0[2]=x2; B0[3]=x3;
      B1[0]=x4; B1[1]=x5; B1[2]=x6; B1[3]=x7;
    }
  };

  // ---- 4 named buffers, 4-unrolled loop: no rotation copies ----
  float4 a0,a1,a2, b0,b1,b2, c0,c1,c2, d0,d1,d2;
  LDr(0, a0,a1,a2);
  if (1 < nv) LDr(1, b0,b1,b2);
  if (2 < nv) LDr(2, c0,c1,c2);
  if (3 < nv) LDr(3, d0,d1,d2);
  int it = 0;
  while (true){
    BODY(a0,a1,a2, it); if (it+4 < nv) LDr(it+4, a0,a1,a2); if (++it >= nv) break;
    BODY(b0,b1,b2, it); if (it+4 < nv) LDr(it+4, b0,b1,b2); if (++it >= nv) break;
    BODY(c0,c1,c2, it); if (it+4 < nv) LDr(it+4, c0,c1,c2); if (++it >= nv) break;
    BODY(d0,d1,d2, it); if (it+4 < nv) LDr(it+4, d0,d1,d2); if (++it >= nv) break;
  }
  RENORM();

  // ---- outputs ----
  float* out = wseg + (size_t)task*SEGSTRIDE;
  #pragma unroll
  for (int r=0;r<16;++r){
    int row = (r&3) + 8*(r>>2) + 4*hi;
    if (row < KK && n < KK) out[row*KK + n] = acc[r];
  }
  if (hi==0 && n<KK) ((int*)out)[NST + n] = cexp;

  #pragma unroll
  for (int o = 32; o > 0; o >>= 1) gold += __shfl_xor(gold, o, 64);
  if (lane == 0) partialG[task] = gold;
}

// ============ pass 2: serial segment applications (<=SEGS steps) ============
template<int SEGL, int SEGS>
__global__ __launch_bounds__(64,1) void chain_kernel2(
    const float* __restrict__ feats, const float* __restrict__ trans,
    const int* __restrict__ targets, const int* __restrict__ lengths,
    const float* __restrict__ wseg, float* __restrict__ partialA)
{
    constexpr float LOG2E = 1.4426950408889634f;
    constexpr float LN2   = 0.6931471805599453f;
    const int b = blockIdx.x;
    const int lane = threadIdx.x;
    const int len = lengths[b];
    const bool act = lane < KK;
    const int li = act ? lane : 0;

    __shared__ __align__(16) float Ul[KK];

    const float* fb = feats + (size_t)b*TT*NST;
    float a2 = fb[li*KK + START_TAG] * LOG2E;
    float c0 = __uint_as_float(__builtin_amdgcn_readfirstlane(__float_as_uint(a2)));
    float CW = c0;
    float wk = act ? fexp2(a2 - c0) : 0.f;

    const int nseg = (len - 1 + SEGL - 1) / SEGL;

    if (act && nseg > 0){
        float4 mA[5], mB[5];
        int cA = 0, cB = 0;
        auto LDM = [&](int s2, float4 (&m)[5], int& c){
            const float* base = wseg + (size_t)(b*SEGS + s2)*SEGSTRIDE;
            const float4* p4 = (const float4*)(base + li*KK);
            m[0]=p4[0]; m[1]=p4[1]; m[2]=p4[2]; m[3]=p4[3]; m[4]=p4[4];
            c = ((const int*)base)[NST + li];
        };
        auto STEP = [&](float4 (&m)[5], int c){
            int e = (int)((__float_as_uint(wk) >> 23) & 255) - 127;
            int q = __builtin_amdgcn_readfirstlane(c + e);   // approx-max exponent (validated R4)
            Ul[li] = ldexpf(wk, c - q);
            asm volatile("s_waitcnt lgkmcnt(0)" ::: "memory");
            const float4* up = (const float4*)Ul;
            float4 u0 = up[0], u1 = up[1], u2 = up[2], u3 = up[3], u4 = up[4];
            float s0 = m[0].x*u0.x, s1 = m[0].y*u0.y;
            s0 = fmaf(m[0].z,u0.z,s0); s1 = fmaf(m[0].w,u0.w,s1);
            s0 = fmaf(m[1].x,u1.x,s0); s1 = fmaf(m[1].y,u1.y,s1);
            s0 = fmaf(m[1].z,u1.z,s0); s1 = fmaf(m[1].w,u1.w,s1);
            s0 = fmaf(m[2].x,u2.x,s0); s1 = fmaf(m[2].y,u2.y,s1);
            s0 = fmaf(m[2].z,u2.z,s0); s1 = fmaf(m[2].w,u2.w,s1);
            s0 = fmaf(m[3].x,u3.x,s0); s1 = fmaf(m[3].y,u3.y,s1);
            s0 = fmaf(m[3].z,u3.z,s0); s1 = fmaf(m[3].w,u3.w,s1);
            s0 = fmaf(m[4].x,u4.x,s0); s1 = fmaf(m[4].y,u4.y,s1);
            s0 = fmaf(m[4].z,u4.z,s0); s1 = fmaf(m[4].w,u4.w,s1);
            wk = s0 + s1;
            CW += (float)q;
            asm volatile("s_waitcnt lgkmcnt(0)" ::: "memory"); // Ul reads done before next write
        };
        LDM(0, mA, cA);
        for (int s2 = 0; s2 < nseg; ){
            if (s2 + 1 < nseg) LDM(s2 + 1, mB, cB);
            STEP(mA, cA);
            ++s2; if (s2 >= nseg) break;
            if (s2 + 1 < nseg) LDM(s2 + 1, mA, cA);
            STEP(mB, cB);
            ++s2;
        }
    }

    float term = act ? wk * fexp2(trans[STOP_TAG*KK + li] * LOG2E) : 0.f;
    #pragma unroll
    for (int o = 32; o > 0; o >>= 1) term += __shfl_xor(term, o, 64);
    if (lane == 0){
        float lse = LN2 * (CW + flog2(term));
        int last = targets[b*TT + len - 1];
        float g0 = fb[targets[b*TT]*KK + START_TAG];   // t=0 gold term (fused)
        partialA[b] = lse - trans[STOP_TAG*KK + last] - g0;
    }
}

// out = sum(partialA) - sum over 8 partialG per b; deterministic
template<int SEGS>
__global__ __launch_bounds__(256) void final_kernel(
    const float* __restrict__ partialA, const float* __restrict__ partialG,
    float* __restrict__ out)
{
    int tid = threadIdx.x;
    float g = 0.f;
    #pragma unroll
    for (int k = 0; k < SEGS; ++k) g += partialG[tid*SEGS + k];
    float v = partialA[tid] - g;
    #pragma unroll
    for (int off = 32; off > 0; off >>= 1) v += __shfl_down(v, off);
    __shared__ float wsum[4];
    if ((tid & 63) == 0) wsum[tid >> 6] = v;
    __syncthreads();
    if (tid == 0) out[0] = wsum[0]+wsum[1]+wsum[2]+wsum[3];
}

// ============ fallback path (proven R1 serial + gold + final) ============
__global__ __launch_bounds__(64,1) void fwd_serial(
    const float* __restrict__ feats, const float* __restrict__ trans,
    const int* __restrict__ targets, const int* __restrict__ lengths,
    float* __restrict__ partialA)
{
    constexpr float LOG2E = 1.4426950408889634f;
    constexpr float LN2   = 0.6931471805599453f;
    const int b    = blockIdx.x;
    const int lane = threadIdx.x;
    const int len  = lengths[b];
    const float* fb = feats + (size_t)b * TT * NST;
    __shared__ __align__(16) float alpha[KK];
    __shared__ __align__(16) float xs[KK];
    const bool act = lane < KK;
    const int  li  = act ? lane : 0;
    if (act) alpha[lane] = fb[lane * KK + START_TAG] * LOG2E;
    __syncthreads();
    float4 b0[5], b1[5], b2[5], b3[5];
    auto LOAD = [&](float4* dst, int t){
        int tc = (t < len) ? t : (len - 1);
        const float4* p = (const float4*)(fb + (size_t)tc * NST + li * KK);
        dst[0]=p[0]; dst[1]=p[1]; dst[2]=p[2]; dst[3]=p[3]; dst[4]=p[4];
    };
    auto STEP = [&](const float4* bufv){
        const float4* ap = (const float4*)alpha;
        float a[KK];
        #pragma unroll
        for (int q = 0; q < 5; ++q){
            float4 av = ap[q];
            a[4*q+0]=av.x; a[4*q+1]=av.y; a[4*q+2]=av.z; a[4*q+3]=av.w;
        }
        float v[KK];
        #pragma unroll
        for (int q = 0; q < 5; ++q){
            v[4*q+0] = bufv[q].x * LOG2E + a[4*q+0];
            v[4*q+1] = bufv[q].y * LOG2E + a[4*q+1];
            v[4*q+2] = bufv[q].z * LOG2E + a[4*q+2];
            v[4*q+3] = bufv[q].w * LOG2E + a[4*q+3];
        }
        float m = v[0];
        #pragma unroll
        for (int j = 1; j < KK; ++j) m = fmaxf(m, v[j]);
        float s = 0.f;
        #pragma unroll
        for (int j = 0; j < KK; ++j) s += fexp2(v[j] - m);
        float na = m + flog2(s);
        __syncthreads();
        if (act) alpha[lane] = na;
        __syncthreads();
    };
    LOAD(b0,1); LOAD(b1,2); LOAD(b2,3); LOAD(b3,4);
    int t = 1;
    while (t < len){
        STEP(b0); LOAD(b0, t+4); ++t; if (t >= len) break;
        STEP(b1); LOAD(b1, t+4); ++t; if (t >= len) break;
        STEP(b2); LOAD(b2, t+4); ++t; if (t >= len) break;
        STEP(b3); LOAD(b3, t+4); ++t;
    }
    if (act) xs[lane] = alpha[lane] + trans[STOP_TAG*KK + lane] * LOG2E;
    __syncthreads();
    if (lane == 0){
        float m = xs[0];
        for (int j = 1; j < KK; ++j) m = fmaxf(m, xs[j]);
        float s = 0.f;
        for (int j = 0; j < KK; ++j) s += fexp2(xs[j] - m);
        float lse = LN2 * (m + flog2(s));
        int last_tag = targets[b*TT + (len-1)];
        partialA[b] = lse - trans[STOP_TAG*KK + last_tag];
    }
}

__global__ __launch_bounds__(256) void gold_kernel(
    const float* __restrict__ feats, const int* __restrict__ targets,
    const int* __restrict__ lengths, float* __restrict__ partialG)
{
    const int b   = blockIdx.x;
    const int tt  = blockIdx.y * 256 + threadIdx.x;
    const int len = lengths[b];
    float val = 0.f;
    if (tt < len){
        int tgt  = targets[b*TT + tt];
        int prev = (tt > 0) ? targets[b*TT + tt - 1] : START_TAG;
        val = feats[((size_t)b*TT + tt)*NST + tgt*KK + prev];
    }
    #pragma unroll
    for (int off = 32; off > 0; off >>= 1) val += __shfl_down(val, off);
    __shared__ float wsum[4];
    if ((threadIdx.x & 63) == 0) wsum[threadIdx.x >> 6] = val;
    __syncthreads();
    if (threadIdx.x == 0)
        partialG[b*gridDim.y + blockIdx.y] = wsum[0]+wsum[1]+wsum[2]+wsum[3];
}

__global__ __launch_bounds__(256) void final_fb(
    const float* __restrict__ partialA, const float* __restrict__ partialG,
    float* __restrict__ out)
{
    int tid = threadIdx.x;
    float v = partialA[tid] - partialG[tid] - partialG[tid + 256];
    #pragma unroll
    for (int off = 32; off > 0; off >>= 1) v += __shfl_down(v, off);
    __shared__ float wsum[4];
    if ((tid & 63) == 0) wsum[tid >> 6] = v;
    __syncthreads();
    if (tid == 0) out[0] = wsum[0]+wsum[1]+wsum[2]+wsum[3];
}

extern "C" void kernel_launch(void* const* d_in, const int* in_sizes, int n_in,
                              void* d_out, int out_size, void* d_ws, size_t ws_size,
                              hipStream_t stream) {
    const float* feats   = (const float*)d_in[0];
    const float* trans   = (const float*)d_in[1];
    const int*   targets = (const int*)d_in[2];
    const int*   lengths = (const int*)d_in[3];

    float* ws       = (float*)d_ws;
    float* partialA = ws;            // 256 floats
    float* partialG = ws + 256;      // 2048 floats (main) / 512 (fallback)
    float* wseg     = ws + WS_SEG_OFF;

    const size_t need64 = (size_t)(WS_SEG_OFF + (size_t)BB*8*SEGSTRIDE) * sizeof(float);

    if (ws_size >= need64){
        seg_mfma<64,8><<<dim3(BB*8), dim3(64), 0, stream>>>(feats, targets, lengths, wseg, partialG);
        chain_kernel2<64,8><<<dim3(BB), dim3(64), 0, stream>>>(feats, trans, targets, lengths, wseg, partialA);
        final_kernel<8><<<dim3(1), dim3(256), 0, stream>>>(partialA, partialG, (float*)d_out);
    } else {
        fwd_serial<<<dim3(BB), dim3(64), 0, stream>>>(feats, trans, targets, lengths, partialA);
        gold_kernel<<<dim3(BB, 2), dim3(256), 0, stream>>>(feats, targets, lengths, partialG);
        final_fb<<<dim3(1), dim3(256), 0, stream>>>(partialA, partialG, (float*)d_out);
    }
}

// Round 13
// 49.048 us; speedup vs baseline: 1.0004x; 1.0004x over previous
//
#include <hip/hip_runtime.h>
#include <math.h>
#include <stdint.h>

#define BB 256
#define TT 512
#define KK 20
#define START_TAG 18
#define STOP_TAG 19
#define NST 400
#define SEGSTRIDE 420        // 400 M + 20 col-exponents
#define WS_SEG_OFF 4096      // floats: partialA[256] + partialG[2048] + pad

typedef __bf16 bf16x8 __attribute__((ext_vector_type(8)));
typedef float f32x16 __attribute__((ext_vector_type(16)));
typedef uint32_t u32x4 __attribute__((ext_vector_type(4)));

__device__ __forceinline__ float fexp2(float x){ float r; asm("v_exp_f32 %0, %1":"=v"(r):"v"(x)); return r; }
__device__ __forceinline__ float flog2(float x){ float r; asm("v_log_f32 %0, %1":"=v"(r):"v"(x)); return r; }
__device__ __forceinline__ uint32_t pk_bf16(float lo, float hi){
  uint32_t r; asm("v_cvt_pk_bf16_f32 %0, %1, %2":"=v"(r):"v"(lo),"v"(hi)); return r;
}
__device__ __forceinline__ void pswap(uint32_t &a, uint32_t &b){
  asm("v_permlane32_swap_b32 %0, %1":"+v"(a),"+v"(b));
}
__device__ __forceinline__ f32x16 mfma_bf16(u32x4 a, u32x4 b, f32x16 c){
  return __builtin_amdgcn_mfma_f32_32x32x16_bf16(
    __builtin_bit_cast(bf16x8,a), __builtin_bit_cast(bf16x8,b), c, 0,0,0);
}

// ============ pass 1: segment 20x20 matrix products via MFMA + fused gold ====
// ONE task (= SEGL consecutive steps) per wave. 4 NAMED row buffers, loop
// unrolled x4 (no register rotation -> counted vmcnt, loads stay in flight).
// Gold gather fused: t is wave-uniform per step, so tgt/prev are uniform;
// the matching lane extracts f[b,t,tgt,prev] from the RAW loaded registers.
// C->B via cvt_pk + permlane32_swap (C/D layout verified R7/R8).
template<int SEGL, int SEGS>
__global__ __launch_bounds__(64) void seg_mfma(
    const float* __restrict__ feats, const int* __restrict__ targets,
    const int* __restrict__ lengths, float* __restrict__ wseg,
    float* __restrict__ partialG)
{
  constexpr float LOG2E = 1.4426950408889634f;
  const int lane = threadIdx.x;
  const int n  = lane & 31;    // A-row / C-col
  const int hi = lane >> 5;    // k-block selector
  const int task = blockIdx.x;
  const int b = task / SEGS;
  const int s = task - b*SEGS;
  const int seg0 = 1 + SEGL*s;
  const int len = lengths[b];
  int nv = len - seg0; nv = nv < 0 ? 0 : (nv > SEGL ? SEGL : nv);
  if (nv <= 0){ if (lane == 0) partialG[task] = 0.f; return; }   // wave-uniform

  const bool rowok = n < KK;
  const int rli = rowok ? n : 0;               // clamp addr, zero later
  const float* rbase = feats + (size_t)(b*TT + seg0)*NST + rli*KK;
  const int off0 = hi ? 8 : 0;
  const int bT = b*TT;

  // ---- identity B (bf16), pad zero ----
  u32x4 B0, B1;
  #pragma unroll
  for (int d=0; d<4; ++d){
    int k0 = hi*8 + 2*d;
    uint32_t v = 0;
    if (k0   == n && n < KK) v |= 0x3F80u;
    if (k0+1 == n && n < KK) v |= 0x3F800000u;
    B0[d] = v;
    int m0 = 16 + hi*8 + 2*d;
    uint32_t u = 0;
    if (m0   == n && n < KK) u |= 0x3F80u;
    if (m0+1 == n && n < KK) u |= 0x3F800000u;
    B1[d] = u;
  }

  int cexp = 0;
  float gold = 0.f;
  f32x16 acc;
  #pragma unroll
  for (int r=0;r<16;++r) acc[r] = 0.f;

  auto LDr = [&](int it, float4 &r0, float4 &r1, float4 &r2){
    const float* p = rbase + (size_t)it*NST;
    r0 = *(const float4*)(p + off0);
    r1 = *(const float4*)(p + off0 + 4);
    r2 = (hi == 0) ? *(const float4*)(p + 16) : make_float4(0.f,0.f,0.f,0.f);
  };

  auto RENORM = [&](){
    float mx = acc[0];
    #pragma unroll
    for (int r=1;r<16;++r) mx = fmaxf(mx, acc[r]);
    mx = fmaxf(mx, __shfl_xor(mx, 32, 64));
    int e = (int)((__float_as_uint(mx) >> 23) & 255) - 127;
    if (e < -100) e = -100;
    float sc = __uint_as_float((uint32_t)(127 - e) << 23);
    #pragma unroll
    for (int r=0;r<16;++r) acc[r] *= sc;
    cexp += e;
  };

  auto BODY = [&](float4 &r0, float4 &r1, float4 &r2, int it){
    // ---- fused gold gather (uniform tgt/prev; raw values) ----
    int t   = seg0 + it;
    int tgt = targets[bT + t];
    int prv = targets[bT + t - 1];
    int hsel = (prv >= 8 && prv < 16) ? 1 : 0;
    int rsel = (prv >= 16) ? 2 : (((prv & 7) >= 4) ? 1 : 0);
    int comp = prv & 3;
    float4 rr = (rsel == 0) ? r0 : ((rsel == 1) ? r1 : r2);
    float vv = (comp==0)?rr.x:((comp==1)?rr.y:((comp==2)?rr.z:rr.w));
    if (n == tgt && hi == hsel) gold += vv;
    // ---- exp2 -> bf16 A fragment ----
    uint32_t w0 = pk_bf16(fexp2(r0.x*LOG2E), fexp2(r0.y*LOG2E));
    uint32_t w1 = pk_bf16(fexp2(r0.z*LOG2E), fexp2(r0.w*LOG2E));
    uint32_t w2 = pk_bf16(fexp2(r1.x*LOG2E), fexp2(r1.y*LOG2E));
    uint32_t w3 = pk_bf16(fexp2(r1.z*LOG2E), fexp2(r1.w*LOG2E));
    uint32_t w4 = pk_bf16(fexp2(r2.x*LOG2E), fexp2(r2.y*LOG2E));
    uint32_t w5 = pk_bf16(fexp2(r2.z*LOG2E), fexp2(r2.w*LOG2E));
    if (!rowok){ w0=0u; w1=0u; w2=0u; w3=0u; }
    if (!(rowok && hi==0)){ w4=0u; w5=0u; }
    u32x4 A0, A1;
    A0[0]=w0; A0[1]=w1; A0[2]=w2; A0[3]=w3;
    A1[0]=w4; A1[1]=w5; A1[2]=0u; A1[3]=0u;
    f32x16 z;
    #pragma unroll
    for (int r=0;r<16;++r) z[r] = 0.f;
    acc = mfma_bf16(A0, B0, z);
    acc = mfma_bf16(A1, B1, acc);
    if (it != nv-1){
      if ((it & 7) == 7) RENORM();
      // ---- C -> B (bf16) via cvt_pk + permlane32_swap ----
      uint32_t x0 = pk_bf16(acc[0],  acc[1]);
      uint32_t x1 = pk_bf16(acc[2],  acc[3]);
      uint32_t x2 = pk_bf16(acc[4],  acc[5]);
      uint32_t x3 = pk_bf16(acc[6],  acc[7]);
      uint32_t x4 = pk_bf16(acc[8],  acc[9]);
      uint32_t x5 = pk_bf16(acc[10], acc[11]);
      uint32_t x6 = pk_bf16(acc[12], acc[13]);
      uint32_t x7 = pk_bf16(acc[14], acc[15]);
      pswap(x0,x2); pswap(x1,x3); pswap(x4,x6); pswap(x5,x7);
      B0[0]=x0; B0[1]=x1; B0[2]=x2; B0[3]=x3;
      B1[0]=x4; B1[1]=x5; B1[2]=x6; B1[3]=x7;
    }
  };

  // ---- 4 named buffers, 4-unrolled loop: no rotation copies ----
  float4 a0,a1,a2, b0,b1,b2, c0,c1,c2, d0,d1,d2;
  LDr(0, a0,a1,a2);
  if (1 < nv) LDr(1, b0,b1,b2);
  if (2 < nv) LDr(2, c0,c1,c2);
  if (3 < nv) LDr(3, d0,d1,d2);
  int it = 0;
  while (true){
    BODY(a0,a1,a2, it); if (it+4 < nv) LDr(it+4, a0,a1,a2); if (++it >= nv) break;
    BODY(b0,b1,b2, it); if (it+4 < nv) LDr(it+4, b0,b1,b2); if (++it >= nv) break;
    BODY(c0,c1,c2, it); if (it+4 < nv) LDr(it+4, c0,c1,c2); if (++it >= nv) break;
    BODY(d0,d1,d2, it); if (it+4 < nv) LDr(it+4, d0,d1,d2); if (++it >= nv) break;
  }
  RENORM();

  // ---- outputs ----
  float* out = wseg + (size_t)task*SEGSTRIDE;
  #pragma unroll
  for (int r=0;r<16;++r){
    int row = (r&3) + 8*(r>>2) + 4*hi;
    if (row < KK && n < KK) out[row*KK + n] = acc[r];
  }
  if (hi==0 && n<KK) ((int*)out)[NST + n] = cexp;

  #pragma unroll
  for (int o = 32; o > 0; o >>= 1) gold += __shfl_xor(gold, o, 64);
  if (lane == 0) partialG[task] = gold;
}

// ============ pass 2: serial segment applications (<=SEGS steps) ============
template<int SEGL, int SEGS>
__global__ __launch_bounds__(64,1) void chain_kernel2(
    const float* __restrict__ feats, const float* __restrict__ trans,
    const int* __restrict__ targets, const int* __restrict__ lengths,
    const float* __restrict__ wseg, float* __restrict__ partialA)
{
    constexpr float LOG2E = 1.4426950408889634f;
    constexpr float LN2   = 0.6931471805599453f;
    const int b = blockIdx.x;
    const int lane = threadIdx.x;
    const int len = lengths[b];
    const bool act = lane < KK;
    const int li = act ? lane : 0;

    __shared__ __align__(16) float Ul[KK];

    const float* fb = feats + (size_t)b*TT*NST;
    float a2 = fb[li*KK + START_TAG] * LOG2E;
    float c0 = __uint_as_float(__builtin_amdgcn_readfirstlane(__float_as_uint(a2)));
    float CW = c0;
    float wk = act ? fexp2(a2 - c0) : 0.f;

    const int nseg = (len - 1 + SEGL - 1) / SEGL;

    if (act && nseg > 0){
        float4 mA[5], mB[5];
        int cA = 0, cB = 0;
        auto LDM = [&](int s2, float4 (&m)[5], int& c){
            const float* base = wseg + (size_t)(b*SEGS + s2)*SEGSTRIDE;
            const float4* p4 = (const float4*)(base + li*KK);
            m[0]=p4[0]; m[1]=p4[1]; m[2]=p4[2]; m[3]=p4[3]; m[4]=p4[4];
            c = ((const int*)base)[NST + li];
        };
        auto STEP = [&](float4 (&m)[5], int c){
            int e = (int)((__float_as_uint(wk) >> 23) & 255) - 127;
            int q = __builtin_amdgcn_readfirstlane(c + e);   // approx-max exponent (validated R4)
            Ul[li] = ldexpf(wk, c - q);
            asm volatile("s_waitcnt lgkmcnt(0)" ::: "memory");
            const float4* up = (const float4*)Ul;
            float4 u0 = up[0], u1 = up[1], u2 = up[2], u3 = up[3], u4 = up[4];
            float s0 = m[0].x*u0.x, s1 = m[0].y*u0.y;
            s0 = fmaf(m[0].z,u0.z,s0); s1 = fmaf(m[0].w,u0.w,s1);
            s0 = fmaf(m[1].x,u1.x,s0); s1 = fmaf(m[1].y,u1.y,s1);
            s0 = fmaf(m[1].z,u1.z,s0); s1 = fmaf(m[1].w,u1.w,s1);
            s0 = fmaf(m[2].x,u2.x,s0); s1 = fmaf(m[2].y,u2.y,s1);
            s0 = fmaf(m[2].z,u2.z,s0); s1 = fmaf(m[2].w,u2.w,s1);
            s0 = fmaf(m[3].x,u3.x,s0); s1 = fmaf(m[3].y,u3.y,s1);
            s0 = fmaf(m[3].z,u3.z,s0); s1 = fmaf(m[3].w,u3.w,s1);
            s0 = fmaf(m[4].x,u4.x,s0); s1 = fmaf(m[4].y,u4.y,s1);
            s0 = fmaf(m[4].z,u4.z,s0); s1 = fmaf(m[4].w,u4.w,s1);
            wk = s0 + s1;
            CW += (float)q;
            asm volatile("s_waitcnt lgkmcnt(0)" ::: "memory"); // Ul reads done before next write
        };
        LDM(0, mA, cA);
        for (int s2 = 0; s2 < nseg; ){
            if (s2 + 1 < nseg) LDM(s2 + 1, mB, cB);
            STEP(mA, cA);
            ++s2; if (s2 >= nseg) break;
            if (s2 + 1 < nseg) LDM(s2 + 1, mA, cA);
            STEP(mB, cB);
            ++s2;
        }
    }

    float term = act ? wk * fexp2(trans[STOP_TAG*KK + li] * LOG2E) : 0.f;
    #pragma unroll
    for (int o = 32; o > 0; o >>= 1) term += __shfl_xor(term, o, 64);
    if (lane == 0){
        float lse = LN2 * (CW + flog2(term));
        int last = targets[b*TT + len - 1];
        float g0 = fb[targets[b*TT]*KK + START_TAG];   // t=0 gold term (fused)
        partialA[b] = lse - trans[STOP_TAG*KK + last] - g0;
    }
}

// out = sum(partialA) - sum over 8 partialG per b; deterministic
template<int SEGS>
__global__ __launch_bounds__(256) void final_kernel(
    const float* __restrict__ partialA, const float* __restrict__ partialG,
    float* __restrict__ out)
{
    int tid = threadIdx.x;
    float g = 0.f;
    #pragma unroll
    for (int k = 0; k < SEGS; ++k) g += partialG[tid*SEGS + k];
    float v = partialA[tid] - g;
    #pragma unroll
    for (int off = 32; off > 0; off >>= 1) v += __shfl_down(v, off);
    __shared__ float wsum[4];
    if ((tid & 63) == 0) wsum[tid >> 6] = v;
    __syncthreads();
    if (tid == 0) out[0] = wsum[0]+wsum[1]+wsum[2]+wsum[3];
}

// ============ fallback path (proven R1 serial + gold + final) ============
__global__ __launch_bounds__(64,1) void fwd_serial(
    const float* __restrict__ feats, const float* __restrict__ trans,
    const int* __restrict__ targets, const int* __restrict__ lengths,
    float* __restrict__ partialA)
{
    constexpr float LOG2E = 1.4426950408889634f;
    constexpr float LN2   = 0.6931471805599453f;
    const int b    = blockIdx.x;
    const int lane = threadIdx.x;
    const int len  = lengths[b];
    const float* fb = feats + (size_t)b * TT * NST;
    __shared__ __align__(16) float alpha[KK];
    __shared__ __align__(16) float xs[KK];
    const bool act = lane < KK;
    const int  li  = act ? lane : 0;
    if (act) alpha[lane] = fb[lane * KK + START_TAG] * LOG2E;
    __syncthreads();
    float4 b0[5], b1[5], b2[5], b3[5];
    auto LOAD = [&](float4* dst, int t){
        int tc = (t < len) ? t : (len - 1);
        const float4* p = (const float4*)(fb + (size_t)tc * NST + li * KK);
        dst[0]=p[0]; dst[1]=p[1]; dst[2]=p[2]; dst[3]=p[3]; dst[4]=p[4];
    };
    auto STEP = [&](const float4* bufv){
        const float4* ap = (const float4*)alpha;
        float a[KK];
        #pragma unroll
        for (int q = 0; q < 5; ++q){
            float4 av = ap[q];
            a[4*q+0]=av.x; a[4*q+1]=av.y; a[4*q+2]=av.z; a[4*q+3]=av.w;
        }
        float v[KK];
        #pragma unroll
        for (int q = 0; q < 5; ++q){
            v[4*q+0] = bufv[q].x * LOG2E + a[4*q+0];
            v[4*q+1] = bufv[q].y * LOG2E + a[4*q+1];
            v[4*q+2] = bufv[q].z * LOG2E + a[4*q+2];
            v[4*q+3] = bufv[q].w * LOG2E + a[4*q+3];
        }
        float m = v[0];
        #pragma unroll
        for (int j = 1; j < KK; ++j) m = fmaxf(m, v[j]);
        float s = 0.f;
        #pragma unroll
        for (int j = 0; j < KK; ++j) s += fexp2(v[j] - m);
        float na = m + flog2(s);
        __syncthreads();
        if (act) alpha[lane] = na;
        __syncthreads();
    };
    LOAD(b0,1); LOAD(b1,2); LOAD(b2,3); LOAD(b3,4);
    int t = 1;
    while (t < len){
        STEP(b0); LOAD(b0, t+4); ++t; if (t >= len) break;
        STEP(b1); LOAD(b1, t+4); ++t; if (t >= len) break;
        STEP(b2); LOAD(b2, t+4); ++t; if (t >= len) break;
        STEP(b3); LOAD(b3, t+4); ++t;
    }
    if (act) xs[lane] = alpha[lane] + trans[STOP_TAG*KK + lane] * LOG2E;
    __syncthreads();
    if (lane == 0){
        float m = xs[0];
        for (int j = 1; j < KK; ++j) m = fmaxf(m, xs[j]);
        float s = 0.f;
        for (int j = 0; j < KK; ++j) s += fexp2(xs[j] - m);
        float lse = LN2 * (m + flog2(s));
        int last_tag = targets[b*TT + (len-1)];
        partialA[b] = lse - trans[STOP_TAG*KK + last_tag];
    }
}

__global__ __launch_bounds__(256) void gold_kernel(
    const float* __restrict__ feats, const int* __restrict__ targets,
    const int* __restrict__ lengths, float* __restrict__ partialG)
{
    const int b   = blockIdx.x;
    const int tt  = blockIdx.y * 256 + threadIdx.x;
    const int len = lengths[b];
    float val = 0.f;
    if (tt < len){
        int tgt  = targets[b*TT + tt];
        int prev = (tt > 0) ? targets[b*TT + tt - 1] : START_TAG;
        val = feats[((size_t)b*TT + tt)*NST + tgt*KK + prev];
    }
    #pragma unroll
    for (int off = 32; off > 0; off >>= 1) val += __shfl_down(val, off);
    __shared__ float wsum[4];
    if ((threadIdx.x & 63) == 0) wsum[threadIdx.x >> 6] = val;
    __syncthreads();
    if (threadIdx.x == 0)
        partialG[b*gridDim.y + blockIdx.y] = wsum[0]+wsum[1]+wsum[2]+wsum[3];
}

__global__ __launch_bounds__(256) void final_fb(
    const float* __restrict__ partialA, const float* __restrict__ partialG,
    float* __restrict__ out)
{
    int tid = threadIdx.x;
    float v = partialA[tid] - partialG[tid] - partialG[tid + 256];
    #pragma unroll
    for (int off = 32; off > 0; off >>= 1) v += __shfl_down(v, off);
    __shared__ float wsum[4];
    if ((tid & 63) == 0) wsum[tid >> 6] = v;
    __syncthreads();
    if (tid == 0) out[0] = wsum[0]+wsum[1]+wsum[2]+wsum[3];
}

extern "C" void kernel_launch(void* const* d_in, const int* in_sizes, int n_in,
                              void* d_out, int out_size, void* d_ws, size_t ws_size,
                              hipStream_t stream) {
    const float* feats   = (const float*)d_in[0];
    const float* trans   = (const float*)d_in[1];
    const int*   targets = (const int*)d_in[2];
    const int*   lengths = (const int*)d_in[3];

    float* ws       = (float*)d_ws;
    float* partialA = ws;            // 256 floats
    float* partialG = ws + 256;      // 2048 floats (main) / 512 (fallback)
    float* wseg     = ws + WS_SEG_OFF;

    const size_t need64 = (size_t)(WS_SEG_OFF + (size_t)BB*8*SEGSTRIDE) * sizeof(float);

    if (ws_size >= need64){
        seg_mfma<64,8><<<dim3(BB*8), dim3(64), 0, stream>>>(feats, targets, lengths, wseg, partialG);
        chain_kernel2<64,8><<<dim3(BB), dim3(64), 0, stream>>>(feats, trans, targets, lengths, wseg, partialA);
        final_kernel<8><<<dim3(1), dim3(256), 0, stream>>>(partialA, partialG, (float*)d_out);
    } else {
        fwd_serial<<<dim3(BB), dim3(64), 0, stream>>>(feats, trans, targets, lengths, partialA);
        gold_kernel<<<dim3(BB, 2), dim3(256), 0, stream>>>(feats, targets, lengths, partialG);
        final_fb<<<dim3(1), dim3(256), 0, stream>>>(partialA, partialG, (float*)d_out);
    }
}

// Round 14
// 45.047 us; speedup vs baseline: 1.0892x; 1.0888x over previous
//
#include <hip/hip_runtime.h>
#include <math.h>
#include <stdint.h>

#define BB 256
#define TT 512
#define KK 20
#define START_TAG 18
#define STOP_TAG 19
#define NST 400
#define SEGSTRIDE 420        // 400 M + 20 col-exponents
#define WS_SEG_OFF 8192      // floats: partialA[256] + partialG[4096] + pad

typedef __bf16 bf16x8 __attribute__((ext_vector_type(8)));
typedef float f32x16 __attribute__((ext_vector_type(16)));
typedef uint32_t u32x4 __attribute__((ext_vector_type(4)));

__device__ __forceinline__ float fexp2(float x){ float r; asm("v_exp_f32 %0, %1":"=v"(r):"v"(x)); return r; }
__device__ __forceinline__ float flog2(float x){ float r; asm("v_log_f32 %0, %1":"=v"(r):"v"(x)); return r; }
__device__ __forceinline__ uint32_t pk_bf16(float lo, float hi){
  uint32_t r; asm("v_cvt_pk_bf16_f32 %0, %1, %2":"=v"(r):"v"(lo),"v"(hi)); return r;
}
__device__ __forceinline__ void pswap(uint32_t &a, uint32_t &b){
  asm("v_permlane32_swap_b32 %0, %1":"+v"(a),"+v"(b));
}
__device__ __forceinline__ f32x16 mfma_bf16(u32x4 a, u32x4 b, f32x16 c){
  return __builtin_amdgcn_mfma_f32_32x32x16_bf16(
    __builtin_bit_cast(bf16x8,a), __builtin_bit_cast(bf16x8,b), c, 0,0,0);
}

// ============ pass 1: segment 20x20 matrix products via MFMA + fused gold ====
// ONE task (= SEGL consecutive steps) per wave; SEGL=32 -> 4096 waves = 16/CU
// (4/SIMD) for latency hiding. 4 NAMED row buffers, loop unrolled x4 (counted
// vmcnt, loads stay in flight). Gold gather fused with targets prefetched one
// step ahead (uniform s_load off the critical path).
// C->B via cvt_pk + permlane32_swap (C/D layout verified R7/R8).
template<int SEGL, int SEGS>
__global__ __launch_bounds__(64) void seg_mfma(
    const float* __restrict__ feats, const int* __restrict__ targets,
    const int* __restrict__ lengths, float* __restrict__ wseg,
    float* __restrict__ partialG)
{
  constexpr float LOG2E = 1.4426950408889634f;
  const int lane = threadIdx.x;
  const int n  = lane & 31;    // A-row / C-col
  const int hi = lane >> 5;    // k-block selector
  const int task = blockIdx.x;
  const int b = task / SEGS;
  const int s = task - b*SEGS;
  const int seg0 = 1 + SEGL*s;
  const int len = lengths[b];
  int nv = len - seg0; nv = nv < 0 ? 0 : (nv > SEGL ? SEGL : nv);
  if (nv <= 0){ if (lane == 0) partialG[task] = 0.f; return; }   // wave-uniform

  const bool rowok = n < KK;
  const int rli = rowok ? n : 0;               // clamp addr, zero later
  const float* rbase = feats + (size_t)(b*TT + seg0)*NST + rli*KK;
  const int off0 = hi ? 8 : 0;
  const int bT = b*TT;

  // ---- identity B (bf16), pad zero ----
  u32x4 B0, B1;
  #pragma unroll
  for (int d=0; d<4; ++d){
    int k0 = hi*8 + 2*d;
    uint32_t v = 0;
    if (k0   == n && n < KK) v |= 0x3F80u;
    if (k0+1 == n && n < KK) v |= 0x3F800000u;
    B0[d] = v;
    int m0 = 16 + hi*8 + 2*d;
    uint32_t u = 0;
    if (m0   == n && n < KK) u |= 0x3F80u;
    if (m0+1 == n && n < KK) u |= 0x3F800000u;
    B1[d] = u;
  }

  int cexp = 0;
  float gold = 0.f;
  f32x16 acc;
  #pragma unroll
  for (int r=0;r<16;++r) acc[r] = 0.f;

  // targets prefetch state (wave-uniform): tg = targets[t], pv = targets[t-1]
  int tg = targets[bT + seg0];
  int pv = targets[bT + seg0 - 1];

  auto LDr = [&](int it, float4 &r0, float4 &r1, float4 &r2){
    const float* p = rbase + (size_t)it*NST;
    r0 = *(const float4*)(p + off0);
    r1 = *(const float4*)(p + off0 + 4);
    r2 = (hi == 0) ? *(const float4*)(p + 16) : make_float4(0.f,0.f,0.f,0.f);
  };

  auto RENORM = [&](){
    float mx = acc[0];
    #pragma unroll
    for (int r=1;r<16;++r) mx = fmaxf(mx, acc[r]);
    mx = fmaxf(mx, __shfl_xor(mx, 32, 64));
    int e = (int)((__float_as_uint(mx) >> 23) & 255) - 127;
    if (e < -100) e = -100;
    float sc = __uint_as_float((uint32_t)(127 - e) << 23);
    #pragma unroll
    for (int r=0;r<16;++r) acc[r] *= sc;
    cexp += e;
  };

  auto BODY = [&](float4 &r0, float4 &r1, float4 &r2, int it){
    // prefetch next step's target (uniform s_load; consumed next BODY)
    int tg_n = (it + 1 < nv) ? targets[bT + seg0 + it + 1] : 0;
    // ---- fused gold gather (uniform tg/pv; raw values) ----
    int hsel = (pv >= 8 && pv < 16) ? 1 : 0;
    int rsel = (pv >= 16) ? 2 : (((pv & 7) >= 4) ? 1 : 0);
    int comp = pv & 3;
    float4 rr = (rsel == 0) ? r0 : ((rsel == 1) ? r1 : r2);
    float vv = (comp==0)?rr.x:((comp==1)?rr.y:((comp==2)?rr.z:rr.w));
    if (n == tg && hi == hsel) gold += vv;
    // ---- exp2 -> bf16 A fragment ----
    uint32_t w0 = pk_bf16(fexp2(r0.x*LOG2E), fexp2(r0.y*LOG2E));
    uint32_t w1 = pk_bf16(fexp2(r0.z*LOG2E), fexp2(r0.w*LOG2E));
    uint32_t w2 = pk_bf16(fexp2(r1.x*LOG2E), fexp2(r1.y*LOG2E));
    uint32_t w3 = pk_bf16(fexp2(r1.z*LOG2E), fexp2(r1.w*LOG2E));
    uint32_t w4 = pk_bf16(fexp2(r2.x*LOG2E), fexp2(r2.y*LOG2E));
    uint32_t w5 = pk_bf16(fexp2(r2.z*LOG2E), fexp2(r2.w*LOG2E));
    if (!rowok){ w0=0u; w1=0u; w2=0u; w3=0u; }
    if (!(rowok && hi==0)){ w4=0u; w5=0u; }
    u32x4 A0, A1;
    A0[0]=w0; A0[1]=w1; A0[2]=w2; A0[3]=w3;
    A1[0]=w4; A1[1]=w5; A1[2]=0u; A1[3]=0u;
    f32x16 z;
    #pragma unroll
    for (int r=0;r<16;++r) z[r] = 0.f;
    acc = mfma_bf16(A0, B0, z);
    acc = mfma_bf16(A1, B1, acc);
    if (it != nv-1){
      if ((it & 7) == 7) RENORM();
      // ---- C -> B (bf16) via cvt_pk + permlane32_swap ----
      uint32_t x0 = pk_bf16(acc[0],  acc[1]);
      uint32_t x1 = pk_bf16(acc[2],  acc[3]);
      uint32_t x2 = pk_bf16(acc[4],  acc[5]);
      uint32_t x3 = pk_bf16(acc[6],  acc[7]);
      uint32_t x4 = pk_bf16(acc[8],  acc[9]);
      uint32_t x5 = pk_bf16(acc[10], acc[11]);
      uint32_t x6 = pk_bf16(acc[12], acc[13]);
      uint32_t x7 = pk_bf16(acc[14], acc[15]);
      pswap(x0,x2); pswap(x1,x3); pswap(x4,x6); pswap(x5,x7);
      B0[0]=x0; B0[1]=x1; B0[2]=x2; B0[3]=x3;
      B1[0]=x4; B1[1]=x5; B1[2]=x6; B1[3]=x7;
    }
    pv = tg; tg = tg_n;
  };

  // ---- 4 named buffers, 4-unrolled loop: no rotation copies ----
  float4 a0,a1,a2, b0,b1,b2, c0,c1,c2, d0,d1,d2;
  LDr(0, a0,a1,a2);
  if (1 < nv) LDr(1, b0,b1,b2);
  if (2 < nv) LDr(2, c0,c1,c2);
  if (3 < nv) LDr(3, d0,d1,d2);
  int it = 0;
  while (true){
    BODY(a0,a1,a2, it); if (it+4 < nv) LDr(it+4, a0,a1,a2); if (++it >= nv) break;
    BODY(b0,b1,b2, it); if (it+4 < nv) LDr(it+4, b0,b1,b2); if (++it >= nv) break;
    BODY(c0,c1,c2, it); if (it+4 < nv) LDr(it+4, c0,c1,c2); if (++it >= nv) break;
    BODY(d0,d1,d2, it); if (it+4 < nv) LDr(it+4, d0,d1,d2); if (++it >= nv) break;
  }
  RENORM();

  // ---- outputs ----
  float* out = wseg + (size_t)task*SEGSTRIDE;
  #pragma unroll
  for (int r=0;r<16;++r){
    int row = (r&3) + 8*(r>>2) + 4*hi;
    if (row < KK && n < KK) out[row*KK + n] = acc[r];
  }
  if (hi==0 && n<KK) ((int*)out)[NST + n] = cexp;

  #pragma unroll
  for (int o = 32; o > 0; o >>= 1) gold += __shfl_xor(gold, o, 64);
  if (lane == 0) partialG[task] = gold;
}

// ============ pass 2: serial segment applications (<=SEGS steps) ============
template<int SEGL, int SEGS>
__global__ __launch_bounds__(64,1) void chain_kernel2(
    const float* __restrict__ feats, const float* __restrict__ trans,
    const int* __restrict__ targets, const int* __restrict__ lengths,
    const float* __restrict__ wseg, float* __restrict__ partialA)
{
    constexpr float LOG2E = 1.4426950408889634f;
    constexpr float LN2   = 0.6931471805599453f;
    const int b = blockIdx.x;
    const int lane = threadIdx.x;
    const int len = lengths[b];
    const bool act = lane < KK;
    const int li = act ? lane : 0;

    __shared__ __align__(16) float Ul[KK];

    const float* fb = feats + (size_t)b*TT*NST;
    float a2 = fb[li*KK + START_TAG] * LOG2E;
    float c0 = __uint_as_float(__builtin_amdgcn_readfirstlane(__float_as_uint(a2)));
    float CW = c0;
    float wk = act ? fexp2(a2 - c0) : 0.f;

    const int nseg = (len - 1 + SEGL - 1) / SEGL;

    if (act && nseg > 0){
        float4 mA[5], mB[5];
        int cA = 0, cB = 0;
        auto LDM = [&](int s2, float4 (&m)[5], int& c){
            const float* base = wseg + (size_t)(b*SEGS + s2)*SEGSTRIDE;
            const float4* p4 = (const float4*)(base + li*KK);
            m[0]=p4[0]; m[1]=p4[1]; m[2]=p4[2]; m[3]=p4[3]; m[4]=p4[4];
            c = ((const int*)base)[NST + li];
        };
        auto STEP = [&](float4 (&m)[5], int c){
            int e = (int)((__float_as_uint(wk) >> 23) & 255) - 127;
            int q = __builtin_amdgcn_readfirstlane(c + e);   // approx-max exponent (validated R4)
            Ul[li] = ldexpf(wk, c - q);
            asm volatile("s_waitcnt lgkmcnt(0)" ::: "memory");
            const float4* up = (const float4*)Ul;
            float4 u0 = up[0], u1 = up[1], u2 = up[2], u3 = up[3], u4 = up[4];
            float s0 = m[0].x*u0.x, s1 = m[0].y*u0.y;
            s0 = fmaf(m[0].z,u0.z,s0); s1 = fmaf(m[0].w,u0.w,s1);
            s0 = fmaf(m[1].x,u1.x,s0); s1 = fmaf(m[1].y,u1.y,s1);
            s0 = fmaf(m[1].z,u1.z,s0); s1 = fmaf(m[1].w,u1.w,s1);
            s0 = fmaf(m[2].x,u2.x,s0); s1 = fmaf(m[2].y,u2.y,s1);
            s0 = fmaf(m[2].z,u2.z,s0); s1 = fmaf(m[2].w,u2.w,s1);
            s0 = fmaf(m[3].x,u3.x,s0); s1 = fmaf(m[3].y,u3.y,s1);
            s0 = fmaf(m[3].z,u3.z,s0); s1 = fmaf(m[3].w,u3.w,s1);
            s0 = fmaf(m[4].x,u4.x,s0); s1 = fmaf(m[4].y,u4.y,s1);
            s0 = fmaf(m[4].z,u4.z,s0); s1 = fmaf(m[4].w,u4.w,s1);
            wk = s0 + s1;
            CW += (float)q;
            asm volatile("s_waitcnt lgkmcnt(0)" ::: "memory"); // Ul reads done before next write
        };
        LDM(0, mA, cA);
        for (int s2 = 0; s2 < nseg; ){
            if (s2 + 1 < nseg) LDM(s2 + 1, mB, cB);
            STEP(mA, cA);
            ++s2; if (s2 >= nseg) break;
            if (s2 + 1 < nseg) LDM(s2 + 1, mA, cA);
            STEP(mB, cB);
            ++s2;
        }
    }

    float term = act ? wk * fexp2(trans[STOP_TAG*KK + li] * LOG2E) : 0.f;
    #pragma unroll
    for (int o = 32; o > 0; o >>= 1) term += __shfl_xor(term, o, 64);
    if (lane == 0){
        float lse = LN2 * (CW + flog2(term));
        int last = targets[b*TT + len - 1];
        float g0 = fb[targets[b*TT]*KK + START_TAG];   // t=0 gold term (fused)
        partialA[b] = lse - trans[STOP_TAG*KK + last] - g0;
    }
}

// out = sum(partialA) - sum over SEGS partialG per b; deterministic
template<int SEGS>
__global__ __launch_bounds__(256) void final_kernel(
    const float* __restrict__ partialA, const float* __restrict__ partialG,
    float* __restrict__ out)
{
    int tid = threadIdx.x;
    float g = 0.f;
    #pragma unroll
    for (int k = 0; k < SEGS; ++k) g += partialG[tid*SEGS + k];
    float v = partialA[tid] - g;
    #pragma unroll
    for (int off = 32; off > 0; off >>= 1) v += __shfl_down(v, off);
    __shared__ float wsum[4];
    if ((tid & 63) == 0) wsum[tid >> 6] = v;
    __syncthreads();
    if (tid == 0) out[0] = wsum[0]+wsum[1]+wsum[2]+wsum[3];
}

// ============ fallback path (proven R1 serial + gold + final) ============
__global__ __launch_bounds__(64,1) void fwd_serial(
    const float* __restrict__ feats, const float* __restrict__ trans,
    const int* __restrict__ targets, const int* __restrict__ lengths,
    float* __restrict__ partialA)
{
    constexpr float LOG2E = 1.4426950408889634f;
    constexpr float LN2   = 0.6931471805599453f;
    const int b    = blockIdx.x;
    const int lane = threadIdx.x;
    const int len  = lengths[b];
    const float* fb = feats + (size_t)b * TT * NST;
    __shared__ __align__(16) float alpha[KK];
    __shared__ __align__(16) float xs[KK];
    const bool act = lane < KK;
    const int  li  = act ? lane : 0;
    if (act) alpha[lane] = fb[lane * KK + START_TAG] * LOG2E;
    __syncthreads();
    float4 b0[5], b1[5], b2[5], b3[5];
    auto LOAD = [&](float4* dst, int t){
        int tc = (t < len) ? t : (len - 1);
        const float4* p = (const float4*)(fb + (size_t)tc * NST + li * KK);
        dst[0]=p[0]; dst[1]=p[1]; dst[2]=p[2]; dst[3]=p[3]; dst[4]=p[4];
    };
    auto STEP = [&](const float4* bufv){
        const float4* ap = (const float4*)alpha;
        float a[KK];
        #pragma unroll
        for (int q = 0; q < 5; ++q){
            float4 av = ap[q];
            a[4*q+0]=av.x; a[4*q+1]=av.y; a[4*q+2]=av.z; a[4*q+3]=av.w;
        }
        float v[KK];
        #pragma unroll
        for (int q = 0; q < 5; ++q){
            v[4*q+0] = bufv[q].x * LOG2E + a[4*q+0];
            v[4*q+1] = bufv[q].y * LOG2E + a[4*q+1];
            v[4*q+2] = bufv[q].z * LOG2E + a[4*q+2];
            v[4*q+3] = bufv[q].w * LOG2E + a[4*q+3];
        }
        float m = v[0];
        #pragma unroll
        for (int j = 1; j < KK; ++j) m = fmaxf(m, v[j]);
        float s = 0.f;
        #pragma unroll
        for (int j = 0; j < KK; ++j) s += fexp2(v[j] - m);
        float na = m + flog2(s);
        __syncthreads();
        if (act) alpha[lane] = na;
        __syncthreads();
    };
    LOAD(b0,1); LOAD(b1,2); LOAD(b2,3); LOAD(b3,4);
    int t = 1;
    while (t < len){
        STEP(b0); LOAD(b0, t+4); ++t; if (t >= len) break;
        STEP(b1); LOAD(b1, t+4); ++t; if (t >= len) break;
        STEP(b2); LOAD(b2, t+4); ++t; if (t >= len) break;
        STEP(b3); LOAD(b3, t+4); ++t;
    }
    if (act) xs[lane] = alpha[lane] + trans[STOP_TAG*KK + lane] * LOG2E;
    __syncthreads();
    if (lane == 0){
        float m = xs[0];
        for (int j = 1; j < KK; ++j) m = fmaxf(m, xs[j]);
        float s = 0.f;
        for (int j = 0; j < KK; ++j) s += fexp2(xs[j] - m);
        float lse = LN2 * (m + flog2(s));
        int last_tag = targets[b*TT + (len-1)];
        partialA[b] = lse - trans[STOP_TAG*KK + last_tag];
    }
}

__global__ __launch_bounds__(256) void gold_kernel(
    const float* __restrict__ feats, const int* __restrict__ targets,
    const int* __restrict__ lengths, float* __restrict__ partialG)
{
    const int b   = blockIdx.x;
    const int tt  = blockIdx.y * 256 + threadIdx.x;
    const int len = lengths[b];
    float val = 0.f;
    if (tt < len){
        int tgt  = targets[b*TT + tt];
        int prev = (tt > 0) ? targets[b*TT + tt - 1] : START_TAG;
        val = feats[((size_t)b*TT + tt)*NST + tgt*KK + prev];
    }
    #pragma unroll
    for (int off = 32; off > 0; off >>= 1) val += __shfl_down(val, off);
    __shared__ float wsum[4];
    if ((threadIdx.x & 63) == 0) wsum[threadIdx.x >> 6] = val;
    __syncthreads();
    if (threadIdx.x == 0)
        partialG[b*gridDim.y + blockIdx.y] = wsum[0]+wsum[1]+wsum[2]+wsum[3];
}

__global__ __launch_bounds__(256) void final_fb(
    const float* __restrict__ partialA, const float* __restrict__ partialG,
    float* __restrict__ out)
{
    int tid = threadIdx.x;
    float v = partialA[tid] - partialG[tid] - partialG[tid + 256];
    #pragma unroll
    for (int off = 32; off > 0; off >>= 1) v += __shfl_down(v, off);
    __shared__ float wsum[4];
    if ((tid & 63) == 0) wsum[tid >> 6] = v;
    __syncthreads();
    if (tid == 0) out[0] = wsum[0]+wsum[1]+wsum[2]+wsum[3];
}

extern "C" void kernel_launch(void* const* d_in, const int* in_sizes, int n_in,
                              void* d_out, int out_size, void* d_ws, size_t ws_size,
                              hipStream_t stream) {
    const float* feats   = (const float*)d_in[0];
    const float* trans   = (const float*)d_in[1];
    const int*   targets = (const int*)d_in[2];
    const int*   lengths = (const int*)d_in[3];

    float* ws       = (float*)d_ws;
    float* partialA = ws;            // 256 floats
    float* partialG = ws + 256;      // 4096 floats (main) / 512 (fallback)
    float* wseg     = ws + WS_SEG_OFF;

    const size_t need32 = (size_t)(WS_SEG_OFF + (size_t)BB*16*SEGSTRIDE) * sizeof(float);

    if (ws_size >= need32){
        seg_mfma<32,16><<<dim3(BB*16), dim3(64), 0, stream>>>(feats, targets, lengths, wseg, partialG);
        chain_kernel2<32,16><<<dim3(BB), dim3(64), 0, stream>>>(feats, trans, targets, lengths, wseg, partialA);
        final_kernel<16><<<dim3(1), dim3(256), 0, stream>>>(partialA, partialG, (float*)d_out);
    } else {
        fwd_serial<<<dim3(BB), dim3(64), 0, stream>>>(feats, trans, targets, lengths, partialA);
        gold_kernel<<<dim3(BB, 2), dim3(256), 0, stream>>>(feats, targets, lengths, partialG);
        final_fb<<<dim3(1), dim3(256), 0, stream>>>(partialA, partialG, (float*)d_out);
    }
}

// Round 15
// 44.172 us; speedup vs baseline: 1.1108x; 1.0198x over previous
//
#include <hip/hip_runtime.h>
#include <math.h>
#include <stdint.h>

#define BB 256
#define TT 512
#define KK 20
#define START_TAG 18
#define STOP_TAG 19
#define NST 400
#define SEGSTRIDE 420        // 400 M + 20 col-exponents
#define WS_SEG_OFF 8192      // floats: partialA[256] + partialG[4096] + pad

typedef __bf16 bf16x8 __attribute__((ext_vector_type(8)));
typedef float f32x16 __attribute__((ext_vector_type(16)));
typedef uint32_t u32x4 __attribute__((ext_vector_type(4)));

__device__ __forceinline__ float fexp2(float x){ float r; asm("v_exp_f32 %0, %1":"=v"(r):"v"(x)); return r; }
__device__ __forceinline__ float flog2(float x){ float r; asm("v_log_f32 %0, %1":"=v"(r):"v"(x)); return r; }
__device__ __forceinline__ uint32_t pk_bf16(float lo, float hi){
  uint32_t r; asm("v_cvt_pk_bf16_f32 %0, %1, %2":"=v"(r):"v"(lo),"v"(hi)); return r;
}
__device__ __forceinline__ void pswap(uint32_t &a, uint32_t &b){
  asm("v_permlane32_swap_b32 %0, %1":"+v"(a),"+v"(b));
}
__device__ __forceinline__ f32x16 mfma_bf16(u32x4 a, u32x4 b, f32x16 c){
  return __builtin_amdgcn_mfma_f32_32x32x16_bf16(
    __builtin_bit_cast(bf16x8,a), __builtin_bit_cast(bf16x8,b), c, 0,0,0);
}

// ============ pass 1: segment 20x20 matrix products via MFMA + fused gold ====
// ONE task (= SEGL consecutive steps) per wave. LOAD-BALANCE SWIZZLE: raw
// block round-robin pins s = blockIdx%SEGS per CU (s=0 CUs get all-full
// segments -> 1.9x makespan). Diagonal remap s=k, b=(c+16k)%256 gives every
// CU all 16 segment positions across 16 batch elements.
// 4 NAMED row buffers (counted vmcnt); targets prefetched one step ahead;
// C->B via cvt_pk + permlane32_swap (layout verified R7/R8).
template<int SEGL, int SEGS>
__global__ __launch_bounds__(64) void seg_mfma(
    const float* __restrict__ feats, const int* __restrict__ targets,
    const int* __restrict__ lengths, float* __restrict__ wseg,
    float* __restrict__ partialG)
{
  constexpr float LOG2E = 1.4426950408889634f;
  const int lane = threadIdx.x;
  const int n  = lane & 31;    // A-row / C-col
  const int hi = lane >> 5;    // k-block selector
  // ---- diagonal task swizzle (bijective): c=blk&255, k=blk>>8 ----
  const int c = blockIdx.x & (BB-1);
  const int k = blockIdx.x >> 8;
  const int s = k;
  const int b = (c + (k << 4)) & (BB-1);
  const int tid2 = b*SEGS + s;               // storage index (b,s)
  const int seg0 = 1 + SEGL*s;
  const int len = lengths[b];
  int nv = len - seg0; nv = nv < 0 ? 0 : (nv > SEGL ? SEGL : nv);
  if (nv <= 0){ if (lane == 0) partialG[tid2] = 0.f; return; }   // wave-uniform

  const bool rowok = n < KK;
  const int rli = rowok ? n : 0;               // clamp addr, zero later
  const float* rbase = feats + (size_t)(b*TT + seg0)*NST + rli*KK;
  const int off0 = hi ? 8 : 0;
  const int bT = b*TT;

  // ---- identity B (bf16), pad zero ----
  u32x4 B0, B1;
  #pragma unroll
  for (int d=0; d<4; ++d){
    int k0 = hi*8 + 2*d;
    uint32_t v = 0;
    if (k0   == n && n < KK) v |= 0x3F80u;
    if (k0+1 == n && n < KK) v |= 0x3F800000u;
    B0[d] = v;
    int m0 = 16 + hi*8 + 2*d;
    uint32_t u = 0;
    if (m0   == n && n < KK) u |= 0x3F80u;
    if (m0+1 == n && n < KK) u |= 0x3F800000u;
    B1[d] = u;
  }

  int cexp = 0;
  float gold = 0.f;
  f32x16 acc;
  #pragma unroll
  for (int r=0;r<16;++r) acc[r] = 0.f;

  // targets prefetch state (wave-uniform): tg = targets[t], pv = targets[t-1]
  int tg = targets[bT + seg0];
  int pv = targets[bT + seg0 - 1];

  auto LDr = [&](int it, float4 &r0, float4 &r1, float4 &r2){
    const float* p = rbase + (size_t)it*NST;
    r0 = *(const float4*)(p + off0);
    r1 = *(const float4*)(p + off0 + 4);
    r2 = (hi == 0) ? *(const float4*)(p + 16) : make_float4(0.f,0.f,0.f,0.f);
  };

  auto RENORM = [&](){
    float mx = acc[0];
    #pragma unroll
    for (int r=1;r<16;++r) mx = fmaxf(mx, acc[r]);
    mx = fmaxf(mx, __shfl_xor(mx, 32, 64));
    int e = (int)((__float_as_uint(mx) >> 23) & 255) - 127;
    if (e < -100) e = -100;
    float sc = __uint_as_float((uint32_t)(127 - e) << 23);
    #pragma unroll
    for (int r=0;r<16;++r) acc[r] *= sc;
    cexp += e;
  };

  auto BODY = [&](float4 &r0, float4 &r1, float4 &r2, int it){
    // prefetch next step's target (uniform s_load; consumed next BODY)
    int tg_n = (it + 1 < nv) ? targets[bT + seg0 + it + 1] : 0;
    // ---- fused gold gather (uniform tg/pv; raw values) ----
    int hsel = (pv >= 8 && pv < 16) ? 1 : 0;
    int rsel = (pv >= 16) ? 2 : (((pv & 7) >= 4) ? 1 : 0);
    int comp = pv & 3;
    float4 rr = (rsel == 0) ? r0 : ((rsel == 1) ? r1 : r2);
    float vv = (comp==0)?rr.x:((comp==1)?rr.y:((comp==2)?rr.z:rr.w));
    if (n == tg && hi == hsel) gold += vv;
    // ---- exp2 -> bf16 A fragment ----
    uint32_t w0 = pk_bf16(fexp2(r0.x*LOG2E), fexp2(r0.y*LOG2E));
    uint32_t w1 = pk_bf16(fexp2(r0.z*LOG2E), fexp2(r0.w*LOG2E));
    uint32_t w2 = pk_bf16(fexp2(r1.x*LOG2E), fexp2(r1.y*LOG2E));
    uint32_t w3 = pk_bf16(fexp2(r1.z*LOG2E), fexp2(r1.w*LOG2E));
    uint32_t w4 = pk_bf16(fexp2(r2.x*LOG2E), fexp2(r2.y*LOG2E));
    uint32_t w5 = pk_bf16(fexp2(r2.z*LOG2E), fexp2(r2.w*LOG2E));
    if (!rowok){ w0=0u; w1=0u; w2=0u; w3=0u; }
    if (!(rowok && hi==0)){ w4=0u; w5=0u; }
    u32x4 A0, A1;
    A0[0]=w0; A0[1]=w1; A0[2]=w2; A0[3]=w3;
    A1[0]=w4; A1[1]=w5; A1[2]=0u; A1[3]=0u;
    f32x16 z;
    #pragma unroll
    for (int r=0;r<16;++r) z[r] = 0.f;
    acc = mfma_bf16(A0, B0, z);
    acc = mfma_bf16(A1, B1, acc);
    if (it != nv-1){
      if ((it & 7) == 7) RENORM();
      // ---- C -> B (bf16) via cvt_pk + permlane32_swap ----
      uint32_t x0 = pk_bf16(acc[0],  acc[1]);
      uint32_t x1 = pk_bf16(acc[2],  acc[3]);
      uint32_t x2 = pk_bf16(acc[4],  acc[5]);
      uint32_t x3 = pk_bf16(acc[6],  acc[7]);
      uint32_t x4 = pk_bf16(acc[8],  acc[9]);
      uint32_t x5 = pk_bf16(acc[10], acc[11]);
      uint32_t x6 = pk_bf16(acc[12], acc[13]);
      uint32_t x7 = pk_bf16(acc[14], acc[15]);
      pswap(x0,x2); pswap(x1,x3); pswap(x4,x6); pswap(x5,x7);
      B0[0]=x0; B0[1]=x1; B0[2]=x2; B0[3]=x3;
      B1[0]=x4; B1[1]=x5; B1[2]=x6; B1[3]=x7;
    }
    pv = tg; tg = tg_n;
  };

  // ---- 4 named buffers, 4-unrolled loop: no rotation copies ----
  float4 a0,a1,a2, b0,b1,b2, c0,c1,c2, d0,d1,d2;
  LDr(0, a0,a1,a2);
  if (1 < nv) LDr(1, b0,b1,b2);
  if (2 < nv) LDr(2, c0,c1,c2);
  if (3 < nv) LDr(3, d0,d1,d2);
  int it = 0;
  while (true){
    BODY(a0,a1,a2, it); if (it+4 < nv) LDr(it+4, a0,a1,a2); if (++it >= nv) break;
    BODY(b0,b1,b2, it); if (it+4 < nv) LDr(it+4, b0,b1,b2); if (++it >= nv) break;
    BODY(c0,c1,c2, it); if (it+4 < nv) LDr(it+4, c0,c1,c2); if (++it >= nv) break;
    BODY(d0,d1,d2, it); if (it+4 < nv) LDr(it+4, d0,d1,d2); if (++it >= nv) break;
  }
  RENORM();

  // ---- outputs (indexed by (b,s) so chain/final are unchanged) ----
  float* out = wseg + (size_t)tid2*SEGSTRIDE;
  #pragma unroll
  for (int r=0;r<16;++r){
    int row = (r&3) + 8*(r>>2) + 4*hi;
    if (row < KK && n < KK) out[row*KK + n] = acc[r];
  }
  if (hi==0 && n<KK) ((int*)out)[NST + n] = cexp;

  #pragma unroll
  for (int o = 32; o > 0; o >>= 1) gold += __shfl_xor(gold, o, 64);
  if (lane == 0) partialG[tid2] = gold;
}

// ============ pass 2: serial segment applications (<=SEGS steps) ============
template<int SEGL, int SEGS>
__global__ __launch_bounds__(64,1) void chain_kernel2(
    const float* __restrict__ feats, const float* __restrict__ trans,
    const int* __restrict__ targets, const int* __restrict__ lengths,
    const float* __restrict__ wseg, float* __restrict__ partialA)
{
    constexpr float LOG2E = 1.4426950408889634f;
    constexpr float LN2   = 0.6931471805599453f;
    const int b = blockIdx.x;
    const int lane = threadIdx.x;
    const int len = lengths[b];
    const bool act = lane < KK;
    const int li = act ? lane : 0;

    __shared__ __align__(16) float Ul[KK];

    const float* fb = feats + (size_t)b*TT*NST;
    float a2 = fb[li*KK + START_TAG] * LOG2E;
    float c0 = __uint_as_float(__builtin_amdgcn_readfirstlane(__float_as_uint(a2)));
    float CW = c0;
    float wk = act ? fexp2(a2 - c0) : 0.f;

    const int nseg = (len - 1 + SEGL - 1) / SEGL;

    if (act && nseg > 0){
        float4 mA[5], mB[5];
        int cA = 0, cB = 0;
        auto LDM = [&](int s2, float4 (&m)[5], int& c){
            const float* base = wseg + (size_t)(b*SEGS + s2)*SEGSTRIDE;
            const float4* p4 = (const float4*)(base + li*KK);
            m[0]=p4[0]; m[1]=p4[1]; m[2]=p4[2]; m[3]=p4[3]; m[4]=p4[4];
            c = ((const int*)base)[NST + li];
        };
        auto STEP = [&](float4 (&m)[5], int c){
            int e = (int)((__float_as_uint(wk) >> 23) & 255) - 127;
            int q = __builtin_amdgcn_readfirstlane(c + e);   // approx-max exponent (validated R4)
            Ul[li] = ldexpf(wk, c - q);
            asm volatile("s_waitcnt lgkmcnt(0)" ::: "memory");
            const float4* up = (const float4*)Ul;
            float4 u0 = up[0], u1 = up[1], u2 = up[2], u3 = up[3], u4 = up[4];
            float s0 = m[0].x*u0.x, s1 = m[0].y*u0.y;
            s0 = fmaf(m[0].z,u0.z,s0); s1 = fmaf(m[0].w,u0.w,s1);
            s0 = fmaf(m[1].x,u1.x,s0); s1 = fmaf(m[1].y,u1.y,s1);
            s0 = fmaf(m[1].z,u1.z,s0); s1 = fmaf(m[1].w,u1.w,s1);
            s0 = fmaf(m[2].x,u2.x,s0); s1 = fmaf(m[2].y,u2.y,s1);
            s0 = fmaf(m[2].z,u2.z,s0); s1 = fmaf(m[2].w,u2.w,s1);
            s0 = fmaf(m[3].x,u3.x,s0); s1 = fmaf(m[3].y,u3.y,s1);
            s0 = fmaf(m[3].z,u3.z,s0); s1 = fmaf(m[3].w,u3.w,s1);
            s0 = fmaf(m[4].x,u4.x,s0); s1 = fmaf(m[4].y,u4.y,s1);
            s0 = fmaf(m[4].z,u4.z,s0); s1 = fmaf(m[4].w,u4.w,s1);
            wk = s0 + s1;
            CW += (float)q;
            asm volatile("s_waitcnt lgkmcnt(0)" ::: "memory"); // Ul reads done before next write
        };
        LDM(0, mA, cA);
        for (int s2 = 0; s2 < nseg; ){
            if (s2 + 1 < nseg) LDM(s2 + 1, mB, cB);
            STEP(mA, cA);
            ++s2; if (s2 >= nseg) break;
            if (s2 + 1 < nseg) LDM(s2 + 1, mA, cA);
            STEP(mB, cB);
            ++s2;
        }
    }

    float term = act ? wk * fexp2(trans[STOP_TAG*KK + li] * LOG2E) : 0.f;
    #pragma unroll
    for (int o = 32; o > 0; o >>= 1) term += __shfl_xor(term, o, 64);
    if (lane == 0){
        float lse = LN2 * (CW + flog2(term));
        int last = targets[b*TT + len - 1];
        float g0 = fb[targets[b*TT]*KK + START_TAG];   // t=0 gold term (fused)
        partialA[b] = lse - trans[STOP_TAG*KK + last] - g0;
    }
}

// out = sum(partialA) - sum over SEGS partialG per b; deterministic
template<int SEGS>
__global__ __launch_bounds__(256) void final_kernel(
    const float* __restrict__ partialA, const float* __restrict__ partialG,
    float* __restrict__ out)
{
    int tid = threadIdx.x;
    float g = 0.f;
    #pragma unroll
    for (int k = 0; k < SEGS; ++k) g += partialG[tid*SEGS + k];
    float v = partialA[tid] - g;
    #pragma unroll
    for (int off = 32; off > 0; off >>= 1) v += __shfl_down(v, off);
    __shared__ float wsum[4];
    if ((tid & 63) == 0) wsum[tid >> 6] = v;
    __syncthreads();
    if (tid == 0) out[0] = wsum[0]+wsum[1]+wsum[2]+wsum[3];
}

// ============ fallback path (proven R1 serial + gold + final) ============
__global__ __launch_bounds__(64,1) void fwd_serial(
    const float* __restrict__ feats, const float* __restrict__ trans,
    const int* __restrict__ targets, const int* __restrict__ lengths,
    float* __restrict__ partialA)
{
    constexpr float LOG2E = 1.4426950408889634f;
    constexpr float LN2   = 0.6931471805599453f;
    const int b    = blockIdx.x;
    const int lane = threadIdx.x;
    const int len  = lengths[b];
    const float* fb = feats + (size_t)b * TT * NST;
    __shared__ __align__(16) float alpha[KK];
    __shared__ __align__(16) float xs[KK];
    const bool act = lane < KK;
    const int  li  = act ? lane : 0;
    if (act) alpha[lane] = fb[lane * KK + START_TAG] * LOG2E;
    __syncthreads();
    float4 b0[5], b1[5], b2[5], b3[5];
    auto LOAD = [&](float4* dst, int t){
        int tc = (t < len) ? t : (len - 1);
        const float4* p = (const float4*)(fb + (size_t)tc * NST + li * KK);
        dst[0]=p[0]; dst[1]=p[1]; dst[2]=p[2]; dst[3]=p[3]; dst[4]=p[4];
    };
    auto STEP = [&](const float4* bufv){
        const float4* ap = (const float4*)alpha;
        float a[KK];
        #pragma unroll
        for (int q = 0; q < 5; ++q){
            float4 av = ap[q];
            a[4*q+0]=av.x; a[4*q+1]=av.y; a[4*q+2]=av.z; a[4*q+3]=av.w;
        }
        float v[KK];
        #pragma unroll
        for (int q = 0; q < 5; ++q){
            v[4*q+0] = bufv[q].x * LOG2E + a[4*q+0];
            v[4*q+1] = bufv[q].y * LOG2E + a[4*q+1];
            v[4*q+2] = bufv[q].z * LOG2E + a[4*q+2];
            v[4*q+3] = bufv[q].w * LOG2E + a[4*q+3];
        }
        float m = v[0];
        #pragma unroll
        for (int j = 1; j < KK; ++j) m = fmaxf(m, v[j]);
        float s = 0.f;
        #pragma unroll
        for (int j = 0; j < KK; ++j) s += fexp2(v[j] - m);
        float na = m + flog2(s);
        __syncthreads();
        if (act) alpha[lane] = na;
        __syncthreads();
    };
    LOAD(b0,1); LOAD(b1,2); LOAD(b2,3); LOAD(b3,4);
    int t = 1;
    while (t < len){
        STEP(b0); LOAD(b0, t+4); ++t; if (t >= len) break;
        STEP(b1); LOAD(b1, t+4); ++t; if (t >= len) break;
        STEP(b2); LOAD(b2, t+4); ++t; if (t >= len) break;
        STEP(b3); LOAD(b3, t+4); ++t;
    }
    if (act) xs[lane] = alpha[lane] + trans[STOP_TAG*KK + lane] * LOG2E;
    __syncthreads();
    if (lane == 0){
        float m = xs[0];
        for (int j = 1; j < KK; ++j) m = fmaxf(m, xs[j]);
        float s = 0.f;
        for (int j = 0; j < KK; ++j) s += fexp2(xs[j] - m);
        float lse = LN2 * (m + flog2(s));
        int last_tag = targets[b*TT + (len-1)];
        partialA[b] = lse - trans[STOP_TAG*KK + last_tag];
    }
}

__global__ __launch_bounds__(256) void gold_kernel(
    const float* __restrict__ feats, const int* __restrict__ targets,
    const int* __restrict__ lengths, float* __restrict__ partialG)
{
    const int b   = blockIdx.x;
    const int tt  = blockIdx.y * 256 + threadIdx.x;
    const int len = lengths[b];
    float val = 0.f;
    if (tt < len){
        int tgt  = targets[b*TT + tt];
        int prev = (tt > 0) ? targets[b*TT + tt - 1] : START_TAG;
        val = feats[((size_t)b*TT + tt)*NST + tgt*KK + prev];
    }
    #pragma unroll
    for (int off = 32; off > 0; off >>= 1) val += __shfl_down(val, off);
    __shared__ float wsum[4];
    if ((threadIdx.x & 63) == 0) wsum[threadIdx.x >> 6] = val;
    __syncthreads();
    if (threadIdx.x == 0)
        partialG[b*gridDim.y + blockIdx.y] = wsum[0]+wsum[1]+wsum[2]+wsum[3];
}

__global__ __launch_bounds__(256) void final_fb(
    const float* __restrict__ partialA, const float* __restrict__ partialG,
    float* __restrict__ out)
{
    int tid = threadIdx.x;
    float v = partialA[tid] - partialG[tid] - partialG[tid + 256];
    #pragma unroll
    for (int off = 32; off > 0; off >>= 1) v += __shfl_down(v, off);
    __shared__ float wsum[4];
    if ((tid & 63) == 0) wsum[tid >> 6] = v;
    __syncthreads();
    if (tid == 0) out[0] = wsum[0]+wsum[1]+wsum[2]+wsum[3];
}

extern "C" void kernel_launch(void* const* d_in, const int* in_sizes, int n_in,
                              void* d_out, int out_size, void* d_ws, size_t ws_size,
                              hipStream_t stream) {
    const float* feats   = (const float*)d_in[0];
    const float* trans   = (const float*)d_in[1];
    const int*   targets = (const int*)d_in[2];
    const int*   lengths = (const int*)d_in[3];

    float* ws       = (float*)d_ws;
    float* partialA = ws;            // 256 floats
    float* partialG = ws + 256;      // 4096 floats (main) / 512 (fallback)
    float* wseg     = ws + WS_SEG_OFF;

    const size_t need32 = (size_t)(WS_SEG_OFF + (size_t)BB*16*SEGSTRIDE) * sizeof(float);

    if (ws_size >= need32){
        seg_mfma<32,16><<<dim3(BB*16), dim3(64), 0, stream>>>(feats, targets, lengths, wseg, partialG);
        chain_kernel2<32,16><<<dim3(BB), dim3(64), 0, stream>>>(feats, trans, targets, lengths, wseg, partialA);
        final_kernel<16><<<dim3(1), dim3(256), 0, stream>>>(partialA, partialG, (float*)d_out);
    } else {
        fwd_serial<<<dim3(BB), dim3(64), 0, stream>>>(feats, trans, targets, lengths, partialA);
        gold_kernel<<<dim3(BB, 2), dim3(256), 0, stream>>>(feats, targets, lengths, partialG);
        final_fb<<<dim3(1), dim3(256), 0, stream>>>(partialA, partialG, (float*)d_out);
    }
}